// Round 8
// baseline (327.345 us; speedup 1.0000x reference)
//
#include <hip/hip_runtime.h>
#include <hip/hip_bf16.h>
#include <string.h>

// CausalSelfAttention on MI355X (gfx950), bf16 MFMA pipeline.
// R8: attention occupancy push — 64-row q-tiles with (p,31-p) pairing: 1024
//     uniform blocks (33 rounds), 4 blocks/CU. V fragments loaded directly
//     from global (tiled Vt, L1-shared across waves) so the LDS pipe stays
//     under the VALU floor; K stays LDS-dbuf. exp2 softmax + ones-MFMA psum.
// D=1024, H=16, Hd=64, B=4, T=2048.

typedef unsigned short u16;
typedef unsigned int u32;
typedef __bf16 bf16x8 __attribute__((ext_vector_type(8)));
typedef float f32x4 __attribute__((ext_vector_type(4)));

#define MFMA16(a, b, c) __builtin_amdgcn_mfma_f32_16x16x32_bf16((a), (b), (c), 0, 0, 0)

__device__ __forceinline__ u16 f2bf(float f) {
  unsigned u = __float_as_uint(f);
  u += 0x7fffu + ((u >> 16) & 1u);  // RNE
  return (u16)(u >> 16);
}

__device__ __forceinline__ u32 pk2bf(float a, float b) {
  __hip_bfloat162 h = __float22bfloat162_rn(make_float2(a, b));  // v_cvt_pk_bf16_f32
  u32 r;
  memcpy(&r, &h, 4);  // register-level no-op
  return r;
}

__device__ __forceinline__ void gload_lds16(const void* g, void* l) {
  __builtin_amdgcn_global_load_lds((const __attribute__((address_space(1))) void*)g,
                                   (__attribute__((address_space(3))) void*)l, 16, 0, 0);
}

// ---------------- cast x (fp32 -> bf16), 4 elems/thread ----------------
__global__ __launch_bounds__(256) void cast_x_kernel(const float* __restrict__ x,
                                                     u16* __restrict__ xb) {
  int i = blockIdx.x * 256 + threadIdx.x;
  float4 v = ((const float4*)x)[i];
  ushort4 o;
  o.x = f2bf(v.x); o.y = f2bf(v.y); o.z = f2bf(v.z); o.w = f2bf(v.w);
  ((ushort4*)xb)[i] = o;
}

// ---------------- transpose-cast W [K][N] fp32 -> Wt [N][K] bf16 ----------------
__global__ __launch_bounds__(256) void tcast_kernel(const float* __restrict__ W,
                                                    u16* __restrict__ Wt, int K, int N) {
  __shared__ float tile[32][33];
  int n0 = blockIdx.x * 32, k0 = blockIdx.y * 32;
  int tx = threadIdx.x & 31, ty = threadIdx.x >> 5;  // 32 x 8
#pragma unroll
  for (int i = 0; i < 4; i++) {
    int k = ty + i * 8;
    tile[k][tx] = W[(size_t)(k0 + k) * N + n0 + tx];
  }
  __syncthreads();
#pragma unroll
  for (int i = 0; i < 4; i++) {
    int n = ty + i * 8;
    Wt[(size_t)(n0 + n) * K + k0 + tx] = f2bf(tile[tx][n]);
  }
}

// ---------------- QKV GEMM: C[8192][3072] = xb @ Wqkvt^T + bias, scatter to Q/K/V ----------------
// Q (first 1024 output cols) additionally scaled by log2(e)/8 so attention can
// use raw v_exp_f32 (= 2^x) with no per-score multiply.
__global__ __launch_bounds__(256) void gemm_qkv_kernel(const u16* __restrict__ A,
                                                       const u16* __restrict__ Bt,
                                                       const float* __restrict__ bias,
                                                       u16* __restrict__ QKV) {
  __shared__ u16 As[128 * 32];
  __shared__ u16 Bs[128 * 32];
  const int tid = threadIdx.x, w = tid >> 6, lane = tid & 63;
  const int g = lane >> 4, c = lane & 15;
  const int wr = w >> 1, wc = w & 1;
  const int m0 = blockIdx.y * 128, n0 = blockIdx.x * 128;
  const int r4 = lane >> 2, c4 = lane & 3;

  f32x4 acc[4][4];
#pragma unroll
  for (int i = 0; i < 4; i++)
#pragma unroll
    for (int j = 0; j < 4; j++) acc[i][j] = (f32x4){0.f, 0.f, 0.f, 0.f};

  for (int k0 = 0; k0 < 1024; k0 += 32) {
    __syncthreads();
#pragma unroll
    for (int i = 0; i < 2; i++) {
      int rowb = w * 32 + i * 16;
      gload_lds16(A + (size_t)(m0 + rowb + r4) * 1024 + k0 + c4 * 8,
                  (char*)As + rowb * 64);
      gload_lds16(Bt + (size_t)(n0 + rowb + r4) * 1024 + k0 + c4 * 8,
                  (char*)Bs + rowb * 64);
    }
    __syncthreads();

    bf16x8 af[4], bf[4];
#pragma unroll
    for (int mt = 0; mt < 4; mt++)
      af[mt] = *(const bf16x8*)(As + (wr * 64 + mt * 16 + c) * 32 + g * 8);
#pragma unroll
    for (int nt = 0; nt < 4; nt++)
      bf[nt] = *(const bf16x8*)(Bs + (wc * 64 + nt * 16 + c) * 32 + g * 8);
#pragma unroll
    for (int mt = 0; mt < 4; mt++)
#pragma unroll
      for (int nt = 0; nt < 4; nt++) acc[mt][nt] = MFMA16(af[mt], bf[nt], acc[mt][nt]);
  }

  const float qscale = (n0 < 1024) ? 0.18033688011112042f : 1.0f;  // log2(e)/8
  float bn[4];
#pragma unroll
  for (int nt = 0; nt < 4; nt++) bn[nt] = bias[n0 + wc * 64 + nt * 16 + c];
#pragma unroll
  for (int mt = 0; mt < 4; mt++) {
#pragma unroll
    for (int r = 0; r < 4; r++) {
      int m = m0 + wr * 64 + mt * 16 + g * 4 + r;  // token index
      int bb = m >> 11, t = m & 2047;
#pragma unroll
      for (int nt = 0; nt < 4; nt++) {
        int n = n0 + wc * 64 + nt * 16 + c;
        int which = n >> 10, rem = n & 1023, h = rem >> 6, d = rem & 63;
        float v = (acc[mt][nt][r] + bn[nt]) * qscale;
        QKV[(size_t)which * 8388608 + (((size_t)(bb * 16 + h) * 2048 + t) * 64 + d)] = f2bf(v);
      }
    }
  }
}

// ---------------- V transpose: V[bh][2048][64] -> Vt tiled [bh][kt][64d][64k] ----------------
__global__ __launch_bounds__(256) void vtrans_kernel(const u16* __restrict__ V,
                                                     u16* __restrict__ Vt) {
  __shared__ u16 tile[64][65];
  int bh = blockIdx.y;
  int kt = blockIdx.x;
  int t0 = kt * 64;
  int tx = threadIdx.x & 63, ty = threadIdx.x >> 6;  // 64 x 4
  const u16* src = V + ((size_t)bh * 2048 + t0) * 64;
#pragma unroll
  for (int i = 0; i < 16; i++) {
    int tr = i * 4 + ty;
    tile[tr][tx] = src[tr * 64 + tx];
  }
  __syncthreads();
  u16* dst = Vt + ((size_t)(bh * 32 + kt)) * 4096;  // [64d][64k] tile
#pragma unroll
  for (int i = 0; i < 16; i++) {
    int d = i * 4 + ty;
    dst[d * 64 + tx] = tile[tx][d];
  }
}

// ---------------- flash attention: 64-row paired q-tiles, V from global ----------------
// grid (16 pairs, 16 heads, 4 batch), 256 threads, 4 blocks/CU. Block handles
// q-tiles p and 31-p (64 rows each) sequentially: (p+1)+(32-p) = 33 uniform
// rounds. Wave w owns q-rows qt*64 + w*16 .. +16 — live in EVERY round; mask
// only on the diagonal round (kt==qt). K staged in LDS dbuf (one barrier per
// round); V B-fragments loaded per-lane from the tiled Vt through L1.
// p = exp2(s) (Q pre-scaled by log2e/8); l via ones-MFMA.
__global__ __launch_bounds__(256, 4) void attn_kernel(const u16* __restrict__ Q,
                                                      const u16* __restrict__ K,
                                                      const u16* __restrict__ Vt,
                                                      u16* __restrict__ ctx) {
  const int pr = blockIdx.x;          // 0..15
  const int qtA = pr, qtB = 31 - pr;  // paired 64-row q-tiles
  const int h = blockIdx.y, b = blockIdx.z;
  const int bh = b * 16 + h;
  const int tid = threadIdx.x, w = tid >> 6, lane = tid & 63;
  const int g = lane >> 4, c = lane & 15;

  const u16* Kg = K + (size_t)bh * 2048 * 64;   // [T][64]
  const u16* Vg = Vt + (size_t)bh * 32 * 4096;  // tiled [kt][64d][64k]

  __shared__ u16 Ks[2][64 * 64];   // K dbuf, XOR-swizzled chunks (16 KB)
  __shared__ u32 Pw[4][16 * 32];   // wave-private packed P^T (8 KB)
  u32* pw = Pw[w];

  // staging lane map (verified swizzle)
  const int srow = lane >> 3;
  const int schunk = (lane & 7) ^ (srow & 7);
  const int cx = c & 7;
  const int off0 = ((g ^ cx) * 8);        // chunk g   (u16 offset)
  const int off1 = (((g ^ cx) ^ 4) * 8);  // chunk g^4
  const int sw = cx << 2;                 // P-buffer 4-dword-block swizzle

  // constant all-ones A-fragment for the psum MFMA
  bf16x8 onesf;
#pragma unroll
  for (int i = 0; i < 8; i++) onesf[i] = (__bf16)1.0f;

  // Q B-fragments for tile A (wave's 16 q-rows; dims 0-31 / 32-63)
  const u16* QgA = Q + ((size_t)bh * 2048 + qtA * 64) * 64;
  bf16x8 aq0 = *(const bf16x8*)(QgA + (w * 16 + c) * 64 + g * 8);
  bf16x8 aq1 = *(const bf16x8*)(QgA + (w * 16 + c) * 64 + 32 + g * 8);

  // prologue: stage K tile 0 (wave w stages rows w*16..w*16+16 => 2 gloads)
#pragma unroll
  for (int i = 0; i < 2; i++) {
    int rbase = w * 16 + i * 8;
    gload_lds16(Kg + (size_t)(rbase + srow) * 64 + schunk * 8, (char*)(Ks[0]) + rbase * 128);
  }
  __syncthreads();

  f32x4 o[4], la;
#pragma unroll
  for (int nt = 0; nt < 4; nt++) o[nt] = (f32x4){0.f, 0.f, 0.f, 0.f};
  la = (f32x4){0.f, 0.f, 0.f, 0.f};

  const int nA = qtA + 1;  // rounds in tile A

  // normalize + packed 8B stores for one finished 64-row q-tile
  auto store_tile = [&](int qbase) {
    float inv = 1.f / la[0];
    int q = qbase + w * 16 + c;
    size_t base = ((size_t)(b * 2048 + q)) * 1024 + h * 64;
#pragma unroll
    for (int nt = 0; nt < 4; nt++) {
      u32 lo = pk2bf(o[nt][0] * inv, o[nt][1] * inv);
      u32 hi = pk2bf(o[nt][2] * inv, o[nt][3] * inv);
      *(uint2*)(ctx + base + nt * 16 + g * 4) = make_uint2(lo, hi);
    }
  };

  for (int r = 0; r < 33; r++) {
    if (r) __syncthreads();  // K tile r staged; all waves done with buf r-1

    // prefetch round r+1's K tile (overlaps compute; drained at next barrier)
    if (r < 32) {
      const int ktn = (r + 1 < nA) ? (r + 1) : (r + 1 - nA);
      const int nb = (r + 1) & 1;
      const u16* Kt = Kg + (size_t)ktn * 4096;
#pragma unroll
      for (int i = 0; i < 2; i++) {
        int rbase = w * 16 + i * 8;
        gload_lds16(Kt + (size_t)(rbase + srow) * 64 + schunk * 8,
                    (char*)(Ks[nb]) + rbase * 128);
      }
    }

    const bool inA = (r < nA);
    const int kt = inA ? r : (r - nA);
    const int qt = inA ? qtA : qtB;

    // V B-fragments direct from global (issued early, consumed after softmax;
    // per-lane contiguous 16B; 4 waves share the 8KB tile via L1)
    const u16* vp = Vg + (size_t)kt * 4096;
    bf16x8 vb0[4], vb1[4];
#pragma unroll
    for (int nt = 0; nt < 4; nt++) {
      vb0[nt] = *(const bf16x8*)(vp + (nt * 16 + c) * 64 + g * 8);
      vb1[nt] = *(const bf16x8*)(vp + (nt * 16 + c) * 64 + 32 + g * 8);
    }

    const u16* Kb = Ks[r & 1];

    // ---- S^T = K . Q^T : 4 key-tiles ----
    f32x4 sa[4];
#pragma unroll
    for (int nt = 0; nt < 4; nt++) {
      bf16x8 k0 = *(const bf16x8*)(Kb + (nt * 16 + c) * 64 + off0);
      bf16x8 k1 = *(const bf16x8*)(Kb + (nt * 16 + c) * 64 + off1);
      f32x4 z = (f32x4){0.f, 0.f, 0.f, 0.f};
      z = MFMA16(k0, aq0, z);  // A=K, B=Q -> S^T[key][q]
      z = MFMA16(k1, aq1, z);
      sa[nt] = z;
    }

    // ---- p = exp2(s), packed P^T write, B-frag read ----
    const bool domask = (kt == qt);  // diagonal round only
    float pe[4][4];
#pragma unroll
    for (int nt = 0; nt < 4; nt++)
#pragma unroll
      for (int rr = 0; rr < 4; rr++) {
        float t = sa[nt][rr];
        if (domask && (nt * 16 + g * 4 + rr) > (w * 16 + c)) t = -1e30f;
        pe[nt][rr] = __builtin_amdgcn_exp2f(t);
      }
#pragma unroll
    for (int nt = 0; nt < 4; nt++) {
      u32 lo = pk2bf(pe[nt][0], pe[nt][1]);
      u32 hi = pk2bf(pe[nt][2], pe[nt][3]);
      *(uint2*)(pw + c * 32 + ((nt * 8 + g * 2) ^ sw)) = make_uint2(lo, hi);
    }
    bf16x8 pB0 = *(const bf16x8*)(pw + c * 32 + ((g * 4) ^ sw));
    bf16x8 pB1 = *(const bf16x8*)(pw + c * 32 + ((16 + g * 4) ^ sw));

    // ---- l += P @ 1 on the MFMA pipe ----
    la = MFMA16(onesf, pB0, la);
    la = MFMA16(onesf, pB1, la);

    // ---- O^T += V^T . P^T : 4 d-tiles ----
#pragma unroll
    for (int nt = 0; nt < 4; nt++) {
      o[nt] = MFMA16(vb0[nt], pB0, o[nt]);
      o[nt] = MFMA16(vb1[nt], pB1, o[nt]);
    }

    // transition: tile A finished -> store, reset, swap to tile B's Q
    if (r == nA - 1) {
      store_tile(qtA * 64);
#pragma unroll
      for (int nt = 0; nt < 4; nt++) o[nt] = (f32x4){0.f, 0.f, 0.f, 0.f};
      la = (f32x4){0.f, 0.f, 0.f, 0.f};
      const u16* QgB = Q + ((size_t)bh * 2048 + qtB * 64) * 64;
      aq0 = *(const bf16x8*)(QgB + (w * 16 + c) * 64 + g * 8);
      aq1 = *(const bf16x8*)(QgB + (w * 16 + c) * 64 + 32 + g * 8);
    }
  }

  store_tile(qtB * 64);
}

// ---------------- out-proj GEMM: out[8192][1024] = ctx @ Woutt^T + bias (fp32 out) ----------------
__global__ __launch_bounds__(256) void gemm_proj_kernel(const u16* __restrict__ A,
                                                        const u16* __restrict__ Bt,
                                                        const float* __restrict__ bias,
                                                        float* __restrict__ out) {
  __shared__ u16 As[128 * 32];
  __shared__ u16 Bs[128 * 32];
  const int tid = threadIdx.x, w = tid >> 6, lane = tid & 63;
  const int g = lane >> 4, c = lane & 15;
  const int wr = w >> 1, wc = w & 1;
  const int m0 = blockIdx.y * 128, n0 = blockIdx.x * 128;
  const int r4 = lane >> 2, c4 = lane & 3;

  f32x4 acc[4][4];
#pragma unroll
  for (int i = 0; i < 4; i++)
#pragma unroll
    for (int j = 0; j < 4; j++) acc[i][j] = (f32x4){0.f, 0.f, 0.f, 0.f};

  for (int k0 = 0; k0 < 1024; k0 += 32) {
    __syncthreads();
#pragma unroll
    for (int i = 0; i < 2; i++) {
      int rowb = w * 32 + i * 16;
      gload_lds16(A + (size_t)(m0 + rowb + r4) * 1024 + k0 + c4 * 8,
                  (char*)As + rowb * 64);
      gload_lds16(Bt + (size_t)(n0 + rowb + r4) * 1024 + k0 + c4 * 8,
                  (char*)Bs + rowb * 64);
    }
    __syncthreads();

    bf16x8 af[4], bf[4];
#pragma unroll
    for (int mt = 0; mt < 4; mt++)
      af[mt] = *(const bf16x8*)(As + (wr * 64 + mt * 16 + c) * 32 + g * 8);
#pragma unroll
    for (int nt = 0; nt < 4; nt++)
      bf[nt] = *(const bf16x8*)(Bs + (wc * 64 + nt * 16 + c) * 32 + g * 8);
#pragma unroll
    for (int mt = 0; mt < 4; mt++)
#pragma unroll
      for (int nt = 0; nt < 4; nt++) acc[mt][nt] = MFMA16(af[mt], bf[nt], acc[mt][nt]);
  }

  float bn[4];
#pragma unroll
  for (int nt = 0; nt < 4; nt++) bn[nt] = bias[n0 + wc * 64 + nt * 16 + c];
#pragma unroll
  for (int mt = 0; mt < 4; mt++)
#pragma unroll
    for (int r = 0; r < 4; r++) {
      int m = m0 + wr * 64 + mt * 16 + g * 4 + r;
#pragma unroll
      for (int nt = 0; nt < 4; nt++) {
        int n = n0 + wc * 64 + nt * 16 + c;
        out[(size_t)m * 1024 + n] = acc[mt][nt][r] + bn[nt];
      }
    }
}

// ---------------- launch ----------------
extern "C" void kernel_launch(void* const* d_in, const int* in_sizes, int n_in,
                              void* d_out, int out_size, void* d_ws, size_t ws_size,
                              hipStream_t stream) {
  const float* x = (const float*)d_in[0];
  const float* Wqkv = (const float*)d_in[1];
  const float* bqkv = (const float*)d_in[2];
  const float* Wout = (const float*)d_in[3];
  const float* bout = (const float*)d_in[4];
  float* out = (float*)d_out;

  char* ws = (char*)d_ws;
  u16* xb  = (u16*)(ws);                    // 16 MB  x bf16 [8192][1024]
  u16* wqt = (u16*)(ws + 16777216);         //  6 MB  Wqkv^T bf16 [3072][1024]
  u16* wot = (u16*)(ws + 23068672);         //  2 MB  Wout^T bf16 [1024][1024]
  u16* Qb  = (u16*)(ws + 25165824);         // 48 MB  QKV bf16 [3][4][16][2048][64]
  u16* Kb  = Qb + 8388608;
  u16* Vb  = Kb + 8388608;
  u16* Vt  = (u16*)(ws + 75497472);         // 16 MB  V^T tiled bf16 [64bh][32kt][64d][64k]
  u16* ctx = (u16*)(ws + 92274688);         // 16 MB  attention out bf16 [8192][1024]

  cast_x_kernel<<<8192, 256, 0, stream>>>(x, xb);
  tcast_kernel<<<dim3(96, 32), 256, 0, stream>>>(Wqkv, wqt, 1024, 3072);
  tcast_kernel<<<dim3(32, 32), 256, 0, stream>>>(Wout, wot, 1024, 1024);
  gemm_qkv_kernel<<<dim3(24, 64), 256, 0, stream>>>(xb, wqt, bqkv, Qb);
  vtrans_kernel<<<dim3(32, 64), 256, 0, stream>>>(Vb, Vt);
  attn_kernel<<<dim3(16, 16, 4), 256, 0, stream>>>(Qb, Kb, Vt, ctx);
  gemm_proj_kernel<<<dim3(8, 64), 256, 0, stream>>>(ctx, wot, bout, out);
}

// Round 9
// 272.457 us; speedup vs baseline: 1.2015x; 1.2015x over previous
//
#include <hip/hip_runtime.h>
#include <hip/hip_bf16.h>
#include <string.h>

// CausalSelfAttention on MI355X (gfx950), bf16 MFMA pipeline.
// R9: attention = R7's paired 128-row q-tile structure (512 blocks, 34 uniform
//     rounds, K/V LDS dbuf, S^T trick, exp2 softmax, ones-MFMA psum) but with
//     512-thread blocks: 8 waves x one 16-row strip each -> 16 waves/CU at the
//     same 147 MB K/V HBM traffic (R8's 64-row tiles doubled traffic: reverted).
// D=1024, H=16, Hd=64, B=4, T=2048.

typedef unsigned short u16;
typedef unsigned int u32;
typedef __bf16 bf16x8 __attribute__((ext_vector_type(8)));
typedef float f32x4 __attribute__((ext_vector_type(4)));

#define MFMA16(a, b, c) __builtin_amdgcn_mfma_f32_16x16x32_bf16((a), (b), (c), 0, 0, 0)

__device__ __forceinline__ u16 f2bf(float f) {
  unsigned u = __float_as_uint(f);
  u += 0x7fffu + ((u >> 16) & 1u);  // RNE
  return (u16)(u >> 16);
}

__device__ __forceinline__ u32 pk2bf(float a, float b) {
  __hip_bfloat162 h = __float22bfloat162_rn(make_float2(a, b));  // v_cvt_pk_bf16_f32
  u32 r;
  memcpy(&r, &h, 4);  // register-level no-op
  return r;
}

__device__ __forceinline__ void gload_lds16(const void* g, void* l) {
  __builtin_amdgcn_global_load_lds((const __attribute__((address_space(1))) void*)g,
                                   (__attribute__((address_space(3))) void*)l, 16, 0, 0);
}

// ---------------- cast x (fp32 -> bf16), 4 elems/thread ----------------
__global__ __launch_bounds__(256) void cast_x_kernel(const float* __restrict__ x,
                                                     u16* __restrict__ xb) {
  int i = blockIdx.x * 256 + threadIdx.x;
  float4 v = ((const float4*)x)[i];
  ushort4 o;
  o.x = f2bf(v.x); o.y = f2bf(v.y); o.z = f2bf(v.z); o.w = f2bf(v.w);
  ((ushort4*)xb)[i] = o;
}

// ---------------- transpose-cast W [K][N] fp32 -> Wt [N][K] bf16 ----------------
__global__ __launch_bounds__(256) void tcast_kernel(const float* __restrict__ W,
                                                    u16* __restrict__ Wt, int K, int N) {
  __shared__ float tile[32][33];
  int n0 = blockIdx.x * 32, k0 = blockIdx.y * 32;
  int tx = threadIdx.x & 31, ty = threadIdx.x >> 5;  // 32 x 8
#pragma unroll
  for (int i = 0; i < 4; i++) {
    int k = ty + i * 8;
    tile[k][tx] = W[(size_t)(k0 + k) * N + n0 + tx];
  }
  __syncthreads();
#pragma unroll
  for (int i = 0; i < 4; i++) {
    int n = ty + i * 8;
    Wt[(size_t)(n0 + n) * K + k0 + tx] = f2bf(tile[tx][n]);
  }
}

// ---------------- QKV GEMM: C[8192][3072] = xb @ Wqkvt^T + bias, scatter to Q/K/V ----------------
// Q (first 1024 output cols) additionally scaled by log2(e)/8 so attention can
// use raw v_exp_f32 (= 2^x) with no per-score multiply.
__global__ __launch_bounds__(256) void gemm_qkv_kernel(const u16* __restrict__ A,
                                                       const u16* __restrict__ Bt,
                                                       const float* __restrict__ bias,
                                                       u16* __restrict__ QKV) {
  __shared__ u16 As[128 * 32];
  __shared__ u16 Bs[128 * 32];
  const int tid = threadIdx.x, w = tid >> 6, lane = tid & 63;
  const int g = lane >> 4, c = lane & 15;
  const int wr = w >> 1, wc = w & 1;
  const int m0 = blockIdx.y * 128, n0 = blockIdx.x * 128;
  const int r4 = lane >> 2, c4 = lane & 3;

  f32x4 acc[4][4];
#pragma unroll
  for (int i = 0; i < 4; i++)
#pragma unroll
    for (int j = 0; j < 4; j++) acc[i][j] = (f32x4){0.f, 0.f, 0.f, 0.f};

  for (int k0 = 0; k0 < 1024; k0 += 32) {
    __syncthreads();
#pragma unroll
    for (int i = 0; i < 2; i++) {
      int rowb = w * 32 + i * 16;
      gload_lds16(A + (size_t)(m0 + rowb + r4) * 1024 + k0 + c4 * 8,
                  (char*)As + rowb * 64);
      gload_lds16(Bt + (size_t)(n0 + rowb + r4) * 1024 + k0 + c4 * 8,
                  (char*)Bs + rowb * 64);
    }
    __syncthreads();

    bf16x8 af[4], bf[4];
#pragma unroll
    for (int mt = 0; mt < 4; mt++)
      af[mt] = *(const bf16x8*)(As + (wr * 64 + mt * 16 + c) * 32 + g * 8);
#pragma unroll
    for (int nt = 0; nt < 4; nt++)
      bf[nt] = *(const bf16x8*)(Bs + (wc * 64 + nt * 16 + c) * 32 + g * 8);
#pragma unroll
    for (int mt = 0; mt < 4; mt++)
#pragma unroll
      for (int nt = 0; nt < 4; nt++) acc[mt][nt] = MFMA16(af[mt], bf[nt], acc[mt][nt]);
  }

  const float qscale = (n0 < 1024) ? 0.18033688011112042f : 1.0f;  // log2(e)/8
  float bn[4];
#pragma unroll
  for (int nt = 0; nt < 4; nt++) bn[nt] = bias[n0 + wc * 64 + nt * 16 + c];
#pragma unroll
  for (int mt = 0; mt < 4; mt++) {
#pragma unroll
    for (int r = 0; r < 4; r++) {
      int m = m0 + wr * 64 + mt * 16 + g * 4 + r;  // token index
      int bb = m >> 11, t = m & 2047;
#pragma unroll
      for (int nt = 0; nt < 4; nt++) {
        int n = n0 + wc * 64 + nt * 16 + c;
        int which = n >> 10, rem = n & 1023, h = rem >> 6, d = rem & 63;
        float v = (acc[mt][nt][r] + bn[nt]) * qscale;
        QKV[(size_t)which * 8388608 + (((size_t)(bb * 16 + h) * 2048 + t) * 64 + d)] = f2bf(v);
      }
    }
  }
}

// ---------------- V transpose: V[bh][2048][64] -> Vt tiled [bh][kt][64d][64k] ----------------
__global__ __launch_bounds__(256) void vtrans_kernel(const u16* __restrict__ V,
                                                     u16* __restrict__ Vt) {
  __shared__ u16 tile[64][65];
  int bh = blockIdx.y;
  int kt = blockIdx.x;
  int t0 = kt * 64;
  int tx = threadIdx.x & 63, ty = threadIdx.x >> 6;  // 64 x 4
  const u16* src = V + ((size_t)bh * 2048 + t0) * 64;
#pragma unroll
  for (int i = 0; i < 16; i++) {
    int tr = i * 4 + ty;
    tile[tr][tx] = src[tr * 64 + tx];
  }
  __syncthreads();
  u16* dst = Vt + ((size_t)(bh * 32 + kt)) * 4096;  // [64d][64k] tile
#pragma unroll
  for (int i = 0; i < 16; i++) {
    int d = i * 4 + ty;
    dst[d * 64 + tx] = tile[tx][d];
  }
}

// ---------------- flash attention: paired 128-row q-tiles, 8 waves x 16 q-rows ----------------
// grid (8 pairs, 16 heads, 4 batch), 512 threads (8 waves). Block handles
// q-tiles p and 15-p (128 rows each) sequentially: 34 uniform rounds.
// Wave w owns q-rows tile_base + w*16 .. +16. K/V staged in LDS dbuf (one
// gload each per wave per round), one barrier per round. S^T = mfma(K, Q);
// p = exp2(s) (Q pre-scaled by log2e/8); l via ones-MFMA; packed P/ctx.
__global__ __launch_bounds__(512, 4) void attn_kernel(const u16* __restrict__ Q,
                                                      const u16* __restrict__ K,
                                                      const u16* __restrict__ Vt,
                                                      u16* __restrict__ ctx) {
  const int pr = blockIdx.x;          // 0..7
  const int qtA = pr, qtB = 15 - pr;  // paired 128-row q-tiles
  const int h = blockIdx.y, b = blockIdx.z;
  const int bh = b * 16 + h;
  const int tid = threadIdx.x, w = tid >> 6, lane = tid & 63;
  const int g = lane >> 4, c = lane & 15;

  const u16* Kg = K + (size_t)bh * 2048 * 64;   // [T][64]
  const u16* Vg = Vt + (size_t)bh * 32 * 4096;  // tiled [kt][64d][64k]

  __shared__ u16 Ks[2][64 * 64];   // K dbuf, XOR-swizzled chunks (16 KB)
  __shared__ u16 Vs[2][64 * 64];   // V dbuf (16 KB)
  __shared__ u32 Pw[8][16 * 32];   // wave-private packed P^T (16 KB)
  u32* pw = Pw[w];

  // staging lane map (verified swizzle); wave w stages rows w*8..w*8+8
  const int srow = lane >> 3;
  const int schunk = (lane & 7) ^ (srow & 7);
  const int cx = c & 7;
  const int off0 = ((g ^ cx) * 8);        // chunk g   (u16 offset)
  const int off1 = (((g ^ cx) ^ 4) * 8);  // chunk g^4
  const int sw = cx << 2;                 // P-buffer 4-dword-block swizzle

  // constant all-ones A-fragment for the psum MFMA
  bf16x8 onesf;
#pragma unroll
  for (int i = 0; i < 8; i++) onesf[i] = (__bf16)1.0f;

  // Q B-fragments for tile A (wave's 16 q-rows; dims 0-31 / 32-63)
  const u16* QgA = Q + ((size_t)bh * 2048 + qtA * 128) * 64;
  bf16x8 aq0 = *(const bf16x8*)(QgA + (w * 16 + c) * 64 + g * 8);
  bf16x8 aq1 = *(const bf16x8*)(QgA + (w * 16 + c) * 64 + 32 + g * 8);

  // prologue: stage K/V tile 0 (1 gload each per wave)
  {
    int rbase = w * 8;
    gload_lds16(Kg + (size_t)(rbase + srow) * 64 + schunk * 8, (char*)(Ks[0]) + rbase * 128);
    gload_lds16(Vg + (size_t)(rbase + srow) * 64 + schunk * 8, (char*)(Vs[0]) + rbase * 128);
  }
  __syncthreads();

  f32x4 o[4], la;
#pragma unroll
  for (int nt = 0; nt < 4; nt++) o[nt] = (f32x4){0.f, 0.f, 0.f, 0.f};
  la = (f32x4){0.f, 0.f, 0.f, 0.f};

  const int nA = 2 * qtA + 2;  // rounds in tile A

  // normalize + packed 8B stores for one finished q-tile (wave's 16 rows)
  auto store_tile = [&](int qbase) {
    float inv = 1.f / la[0];
    int q = qbase + w * 16 + c;
    size_t base = ((size_t)(b * 2048 + q)) * 1024 + h * 64;
#pragma unroll
    for (int nt = 0; nt < 4; nt++) {
      u32 lo = pk2bf(o[nt][0] * inv, o[nt][1] * inv);
      u32 hi = pk2bf(o[nt][2] * inv, o[nt][3] * inv);
      *(uint2*)(ctx + base + nt * 16 + g * 4) = make_uint2(lo, hi);
    }
  };

  for (int r = 0; r < 34; r++) {
    if (r) __syncthreads();  // tile r staged; all waves done with buf r-1

    // prefetch round r+1's K/V tile (overlaps compute; drained at next barrier)
    if (r < 33) {
      const int ktn = (r + 1 < nA) ? (r + 1) : (r + 1 - nA);
      const int nb = (r + 1) & 1;
      int rbase = w * 8;
      gload_lds16(Kg + (size_t)ktn * 4096 + (size_t)(rbase + srow) * 64 + schunk * 8,
                  (char*)(Ks[nb]) + rbase * 128);
      gload_lds16(Vg + (size_t)ktn * 4096 + (size_t)(rbase + srow) * 64 + schunk * 8,
                  (char*)(Vs[nb]) + rbase * 128);
    }

    const bool inA = (r < nA);
    const int kt = inA ? r : (r - nA);
    const int qbase = inA ? qtA * 128 : qtB * 128;
    const int sb0 = qbase + w * 16;  // wave's first q-row
    const int kb = kt * 64;          // round's first key

    if (kb <= sb0 + 15) {  // wave-uniform: wave live this round
      const u16* Kb = Ks[r & 1];
      const u16* Vb = Vs[r & 1];

      // ---- S^T = K . Q^T : 4 key-tiles ----
      f32x4 sa[4];
#pragma unroll
      for (int nt = 0; nt < 4; nt++) {
        bf16x8 k0 = *(const bf16x8*)(Kb + (nt * 16 + c) * 64 + off0);
        bf16x8 k1 = *(const bf16x8*)(Kb + (nt * 16 + c) * 64 + off1);
        f32x4 z = (f32x4){0.f, 0.f, 0.f, 0.f};
        z = MFMA16(k0, aq0, z);  // A=K, B=Q -> S^T[key][q]
        z = MFMA16(k1, aq1, z);
        sa[nt] = z;
      }

      // ---- p = exp2(s), packed P^T write, B-frag read ----
      const bool domask = (kb + 63 > sb0);
      float pe[4][4];
#pragma unroll
      for (int nt = 0; nt < 4; nt++)
#pragma unroll
        for (int rr = 0; rr < 4; rr++) {
          float t = sa[nt][rr];
          if (domask && (kb + nt * 16 + g * 4 + rr) > (sb0 + c)) t = -1e30f;
          pe[nt][rr] = __builtin_amdgcn_exp2f(t);
        }
#pragma unroll
      for (int nt = 0; nt < 4; nt++) {
        u32 lo = pk2bf(pe[nt][0], pe[nt][1]);
        u32 hi = pk2bf(pe[nt][2], pe[nt][3]);
        *(uint2*)(pw + c * 32 + ((nt * 8 + g * 2) ^ sw)) = make_uint2(lo, hi);
      }
      bf16x8 pB0 = *(const bf16x8*)(pw + c * 32 + ((g * 4) ^ sw));
      bf16x8 pB1 = *(const bf16x8*)(pw + c * 32 + ((16 + g * 4) ^ sw));

      // ---- l += P @ 1 on the MFMA pipe ----
      la = MFMA16(onesf, pB0, la);
      la = MFMA16(onesf, pB1, la);

      // ---- O^T += V^T . P^T : 4 d-tiles ----
#pragma unroll
      for (int nt = 0; nt < 4; nt++) {
        bf16x8 v0 = *(const bf16x8*)(Vb + (nt * 16 + c) * 64 + off0);
        bf16x8 v1 = *(const bf16x8*)(Vb + (nt * 16 + c) * 64 + off1);
        o[nt] = MFMA16(v0, pB0, o[nt]);
        o[nt] = MFMA16(v1, pB1, o[nt]);
      }
    }

    // transition: tile A finished -> store, reset, swap to tile B's Q
    if (r == nA - 1) {
      store_tile(qtA * 128);
#pragma unroll
      for (int nt = 0; nt < 4; nt++) o[nt] = (f32x4){0.f, 0.f, 0.f, 0.f};
      la = (f32x4){0.f, 0.f, 0.f, 0.f};
      const u16* QgB = Q + ((size_t)bh * 2048 + qtB * 128) * 64;
      aq0 = *(const bf16x8*)(QgB + (w * 16 + c) * 64 + g * 8);
      aq1 = *(const bf16x8*)(QgB + (w * 16 + c) * 64 + 32 + g * 8);
    }
  }

  store_tile(qtB * 128);
}

// ---------------- out-proj GEMM: out[8192][1024] = ctx @ Woutt^T + bias (fp32 out) ----------------
__global__ __launch_bounds__(256) void gemm_proj_kernel(const u16* __restrict__ A,
                                                        const u16* __restrict__ Bt,
                                                        const float* __restrict__ bias,
                                                        float* __restrict__ out) {
  __shared__ u16 As[128 * 32];
  __shared__ u16 Bs[128 * 32];
  const int tid = threadIdx.x, w = tid >> 6, lane = tid & 63;
  const int g = lane >> 4, c = lane & 15;
  const int wr = w >> 1, wc = w & 1;
  const int m0 = blockIdx.y * 128, n0 = blockIdx.x * 128;
  const int r4 = lane >> 2, c4 = lane & 3;

  f32x4 acc[4][4];
#pragma unroll
  for (int i = 0; i < 4; i++)
#pragma unroll
    for (int j = 0; j < 4; j++) acc[i][j] = (f32x4){0.f, 0.f, 0.f, 0.f};

  for (int k0 = 0; k0 < 1024; k0 += 32) {
    __syncthreads();
#pragma unroll
    for (int i = 0; i < 2; i++) {
      int rowb = w * 32 + i * 16;
      gload_lds16(A + (size_t)(m0 + rowb + r4) * 1024 + k0 + c4 * 8,
                  (char*)As + rowb * 64);
      gload_lds16(Bt + (size_t)(n0 + rowb + r4) * 1024 + k0 + c4 * 8,
                  (char*)Bs + rowb * 64);
    }
    __syncthreads();

    bf16x8 af[4], bf[4];
#pragma unroll
    for (int mt = 0; mt < 4; mt++)
      af[mt] = *(const bf16x8*)(As + (wr * 64 + mt * 16 + c) * 32 + g * 8);
#pragma unroll
    for (int nt = 0; nt < 4; nt++)
      bf[nt] = *(const bf16x8*)(Bs + (wc * 64 + nt * 16 + c) * 32 + g * 8);
#pragma unroll
    for (int mt = 0; mt < 4; mt++)
#pragma unroll
      for (int nt = 0; nt < 4; nt++) acc[mt][nt] = MFMA16(af[mt], bf[nt], acc[mt][nt]);
  }

  float bn[4];
#pragma unroll
  for (int nt = 0; nt < 4; nt++) bn[nt] = bias[n0 + wc * 64 + nt * 16 + c];
#pragma unroll
  for (int mt = 0; mt < 4; mt++)
#pragma unroll
    for (int r = 0; r < 4; r++) {
      int m = m0 + wr * 64 + mt * 16 + g * 4 + r;
#pragma unroll
      for (int nt = 0; nt < 4; nt++) {
        int n = n0 + wc * 64 + nt * 16 + c;
        out[(size_t)m * 1024 + n] = acc[mt][nt][r] + bn[nt];
      }
    }
}

// ---------------- launch ----------------
extern "C" void kernel_launch(void* const* d_in, const int* in_sizes, int n_in,
                              void* d_out, int out_size, void* d_ws, size_t ws_size,
                              hipStream_t stream) {
  const float* x = (const float*)d_in[0];
  const float* Wqkv = (const float*)d_in[1];
  const float* bqkv = (const float*)d_in[2];
  const float* Wout = (const float*)d_in[3];
  const float* bout = (const float*)d_in[4];
  float* out = (float*)d_out;

  char* ws = (char*)d_ws;
  u16* xb  = (u16*)(ws);                    // 16 MB  x bf16 [8192][1024]
  u16* wqt = (u16*)(ws + 16777216);         //  6 MB  Wqkv^T bf16 [3072][1024]
  u16* wot = (u16*)(ws + 23068672);         //  2 MB  Wout^T bf16 [1024][1024]
  u16* Qb  = (u16*)(ws + 25165824);         // 48 MB  QKV bf16 [3][4][16][2048][64]
  u16* Kb  = Qb + 8388608;
  u16* Vb  = Kb + 8388608;
  u16* Vt  = (u16*)(ws + 75497472);         // 16 MB  V^T tiled bf16 [64bh][32kt][64d][64k]
  u16* ctx = (u16*)(ws + 92274688);         // 16 MB  attention out bf16 [8192][1024]

  cast_x_kernel<<<8192, 256, 0, stream>>>(x, xb);
  tcast_kernel<<<dim3(96, 32), 256, 0, stream>>>(Wqkv, wqt, 1024, 3072);
  tcast_kernel<<<dim3(32, 32), 256, 0, stream>>>(Wout, wot, 1024, 1024);
  gemm_qkv_kernel<<<dim3(24, 64), 256, 0, stream>>>(xb, wqt, bqkv, Qb);
  vtrans_kernel<<<dim3(32, 64), 256, 0, stream>>>(Vb, Vt);
  attn_kernel<<<dim3(8, 16, 4), 512, 0, stream>>>(Qb, Kb, Vt, ctx);
  gemm_proj_kernel<<<dim3(8, 64), 256, 0, stream>>>(ctx, wot, bout, out);
}